// Round 7
// baseline (121.285 us; speedup 1.0000x reference)
//
#include <hip/hip_runtime.h>

// UVCrossAttention — MI355X (gfx950), Round 10: monolith, direct-global MFMA
// operands + deeper load pipelining.
//
// R9 post-mortem: mono ≈ 36 µs (out of top-5; dur 102 − ~65.5 fixed residue),
// vs ~13 µs per-CU L2-BW floor. Both split halves are latency-limited:
// value half had a serial global→pack→ds_write→lgkm→ds_read→MFMA chain per
// 32-row subtile; off/aw half only 4-deep load pipelining. This round:
//   * value B-fragments loaded DIRECTLY from global into registers (lane
//     (col,g) reads 8 floats of its row) — no LDS round-trip, no barriers,
//     unroll-2 fragments = 16 dwordx4 in flight.
//   * keyp's W_v B-fragments likewise direct-global (64 KB, L2-hot) —
//     removes the 32 KB sval staging; LDS 59.9 -> 28 KB.
//   * off/aw stream unroll 4 -> 8 (2x in-flight loads).
// One dispatch, zero workspace, 5 -> 4 barriers. 256 blocks x 512 thr.

#define NQ   1024
#define NV   1024
#define ND   128
#define NP   4
#define IMG_W 32
#define IMG_H 32
#define QB   4

typedef __attribute__((ext_vector_type(8))) short bfx8;
typedef __attribute__((ext_vector_type(4))) float f32x4;
typedef __attribute__((ext_vector_type(8))) float f32x8;

__device__ __forceinline__ unsigned short bf_rne(float f) {
  unsigned u = __float_as_uint(f);
  return (unsigned short)((u + 0x7FFFu + ((u >> 16) & 1u)) >> 16);
}
__device__ __forceinline__ float bf2f(unsigned short u) {
  return __uint_as_float((unsigned)u << 16);
}
__device__ __forceinline__ bfx8 pack8(const float* p) {
  bfx8 v;
#pragma unroll
  for (int j = 0; j < 8; ++j) v[j] = (short)bf_rne(p[j]);
  return v;
}

__global__ __launch_bounds__(512) void mono_kernel(
    const float* __restrict__ query, const float* __restrict__ key,
    const float* __restrict__ value, const float* __restrict__ ref3d,
    const float* __restrict__ W_off, const float* __restrict__ b_off,
    const float* __restrict__ W_attn, const float* __restrict__ b_attn,
    const float* __restrict__ W_v, const float* __restrict__ b_v,
    const float* __restrict__ W_o, const float* __restrict__ b_o,
    float* __restrict__ out) {
  __shared__ float q_lds[QB][128];                    // 2 KB
  __shared__ float key_lds[QB][128];                  // 2 KB
  __shared__ float keyp_lds[QB][128];                 // 2 KB
  __shared__ float c_lds[QB];
  __shared__ unsigned short img_bf[QB][NV];           // 8 KB
  __shared__ unsigned short off_bf[QB][1024];         // 8 KB
  __shared__ unsigned short aw_bf[QB][512];           // 4 KB
  __shared__ float o1s[QB][128];                      // 2 KB   (~28 KB total)

  const int tid = threadIdx.x;
  const int q0 = blockIdx.x * QB;
  const int w = tid >> 6, l = tid & 63;
  const int col = l & 15, g = l >> 4;

  // ---- 1. stage q & key rows (coalesced float4)
  if (tid < 128) {
    ((float4*)q_lds)[tid] = ((const float4*)(query + (size_t)q0 * 128))[tid];
  } else if (tid < 256) {
    ((float4*)key_lds)[tid - 128] =
        ((const float4*)(key + (size_t)q0 * 128))[tid - 128];
  }
  __syncthreads();

  // ---- 2. keyp = key @ W_v^T (all 8 waves; W_v B-frags DIRECT from global)
  {
    bfx8 afK[4];
#pragma unroll
    for (int ks = 0; ks < 4; ++ks) {
      bfx8 a;
      if (col < QB) {
        a = pack8(&key_lds[col][ks * 32 + g * 8]);
      } else {
#pragma unroll
        for (int j = 0; j < 8; ++j) a[j] = 0;
      }
      afK[ks] = a;
    }
    {
      const float* wvp = W_v + (size_t)(w * 16 + col) * 128 + g * 8;
      f32x8 raw[4];
#pragma unroll
      for (int ks = 0; ks < 4; ++ks)
        raw[ks] = *(const f32x8*)(wvp + ks * 32);
      f32x4 acc = {0.f, 0.f, 0.f, 0.f};
#pragma unroll
      for (int ks = 0; ks < 4; ++ks) {
        bfx8 b;
#pragma unroll
        for (int j = 0; j < 8; ++j) b[j] = (short)bf_rne(raw[ks][j]);
        acc = __builtin_amdgcn_mfma_f32_16x16x32_bf16(afK[ks], b, acc,
                                                      0, 0, 0);
      }
      if (g == 0) {
#pragma unroll
        for (int i = 0; i < QB; ++i) keyp_lds[i][w * 16 + col] = acc[i];
      }
    }
    if (tid < QB) {   // c[qq] = key[qq]·b_v (b_v == 0 here; kept for generality)
      float s = 0.f;
      for (int e = 0; e < 128; e += 4) {
        const float4 bv = *(const float4*)(b_v + e);
        const float4 k4 = *(const float4*)(&key_lds[tid][e]);
        s = fmaf(bv.x, k4.x,
            fmaf(bv.y, k4.y, fmaf(bv.z, k4.z, fmaf(bv.w, k4.w, s))));
      }
      c_lds[tid] = s;
    }
  }
  __syncthreads();

  // ---- 3. SPLIT: waves 0-3 -> off/aw streaming; waves 4-7 -> img MFMA
  if (w < 4) {
    // thread t (0..255) owns off cols 4t..4t+3, aw cols 2t..2t+1
    const int t = tid;
    float4 aoff[QB];
    float2 aaw[QB];
#pragma unroll
    for (int qq = 0; qq < QB; ++qq) {
      aoff[qq] = make_float4(0.f, 0.f, 0.f, 0.f);
      aaw[qq] = make_float2(0.f, 0.f);
    }
    const float* wo_p = W_off + (size_t)t * 4;
    const float* wa_p = W_attn + (size_t)t * 2;
#pragma unroll 8
    for (int e4 = 0; e4 < 32; ++e4) {
      float4 q4[QB];
#pragma unroll
      for (int qq = 0; qq < QB; ++qq)
        q4[qq] = *(const float4*)(&q_lds[qq][e4 * 4]);
#pragma unroll
      for (int j = 0; j < 4; ++j) {
        const int e = e4 * 4 + j;
        const float4 w4 = *(const float4*)(wo_p + (size_t)e * 1024);
        const float2 w2 = *(const float2*)(wa_p + (size_t)e * 512);
#pragma unroll
        for (int qq = 0; qq < QB; ++qq) {
          const float* qp = (const float*)&q4[qq];
          const float qv = qp[j];            // static extract (j unrolled)
          aoff[qq].x = fmaf(qv, w4.x, aoff[qq].x);
          aoff[qq].y = fmaf(qv, w4.y, aoff[qq].y);
          aoff[qq].z = fmaf(qv, w4.z, aoff[qq].z);
          aoff[qq].w = fmaf(qv, w4.w, aoff[qq].w);
          aaw[qq].x = fmaf(qv, w2.x, aaw[qq].x);
          aaw[qq].y = fmaf(qv, w2.y, aaw[qq].y);
        }
      }
    }
    const float4 bo4 = *(const float4*)(b_off + t * 4);
    const float2 ba2 = *(const float2*)(b_attn + t * 2);
#pragma unroll
    for (int qq = 0; qq < QB; ++qq) {
      const unsigned lo = (unsigned)bf_rne(aoff[qq].x + bo4.x) |
                          ((unsigned)bf_rne(aoff[qq].y + bo4.y) << 16);
      const unsigned hi = (unsigned)bf_rne(aoff[qq].z + bo4.z) |
                          ((unsigned)bf_rne(aoff[qq].w + bo4.w) << 16);
      *(uint2*)(&off_bf[qq][t * 4]) = make_uint2(lo, hi);
      *(unsigned*)(&aw_bf[qq][t * 2]) =
          (unsigned)bf_rne(aaw[qq].x + ba2.x) |
          ((unsigned)bf_rne(aaw[qq].y + ba2.y) << 16);
    }
  } else {
    // wave ww owns v rows ww*256..+255 as 16 fragments of 16 rows.
    // B-fragments DIRECT from global: lane(col,g) reads value row
    // vbase+col, floats ks*32+g*8..+7 (16 x 128B segments per wave).
    const int ww = w - 4;
    bfx8 afrag[4];
#pragma unroll
    for (int ks = 0; ks < 4; ++ks) {
      bfx8 a;
      if (col < QB) {
        a = pack8(&keyp_lds[col][ks * 32 + g * 8]);
      } else {
#pragma unroll
        for (int j = 0; j < 8; ++j) a[j] = 0;
      }
      afrag[ks] = a;
    }
    float cq[QB];
#pragma unroll
    for (int i = 0; i < QB; ++i) cq[i] = c_lds[i];

    const float* rowp = value + (size_t)(ww * 256 + col) * 128 + g * 8;
#pragma unroll 2
    for (int f = 0; f < 16; ++f) {
      const float* rp = rowp + (size_t)f * 16 * 128;
      f32x8 raw[4];
#pragma unroll
      for (int ks = 0; ks < 4; ++ks)
        raw[ks] = *(const f32x8*)(rp + ks * 32);
      f32x4 acc = {0.f, 0.f, 0.f, 0.f};
#pragma unroll
      for (int ks = 0; ks < 4; ++ks) {
        bfx8 b;
#pragma unroll
        for (int j = 0; j < 8; ++j) b[j] = (short)bf_rne(raw[ks][j]);
        acc = __builtin_amdgcn_mfma_f32_16x16x32_bf16(afrag[ks], b, acc,
                                                      0, 0, 0);
      }
      if (g == 0) {
        const int v = ww * 256 + f * 16 + col;
#pragma unroll
        for (int i = 0; i < QB; ++i)
          img_bf[i][v] = bf_rne(acc[i] + cq[i]);
      }
    }
  }
  __syncthreads();

  // ---- 4. sampling: (qq,d) = (tid>>7, tid&127)
  {
    const int qq = tid >> 7;
    const int q = q0 + qq;
    const int d = tid & 127;
    const unsigned short* im = img_bf[qq];
    const size_t qe = (size_t)q * ND + d;

    const float rx = ref3d[qe * 2 + 0];
    const float ry = ref3d[qe * 2 + 1];

    const uint2 ua = *(const uint2*)(&aw_bf[qq][d * 4]);
    const float a0 = bf2f((unsigned short)(ua.x & 0xffff));
    const float a1 = bf2f((unsigned short)(ua.x >> 16));
    const float a2 = bf2f((unsigned short)(ua.y & 0xffff));
    const float a3 = bf2f((unsigned short)(ua.y >> 16));
    const float mx = fmaxf(fmaxf(a0, a1), fmaxf(a2, a3));
    const float e0 = __expf(a0 - mx), e1 = __expf(a1 - mx),
                e2 = __expf(a2 - mx), e3 = __expf(a3 - mx);
    const float inv = 1.0f / (e0 + e1 + e2 + e3);
    const float wgt4[4] = {e0 * inv, e1 * inv, e2 * inv, e3 * inv};

    const uint4 uo = *(const uint4*)(&off_bf[qq][d * 8]);
    const unsigned ox[4] = {uo.x, uo.y, uo.z, uo.w};

    float acc = 0.0f;
#pragma unroll
    for (int p = 0; p < NP; ++p) {
      const float x = rx * (float)IMG_W + bf2f((unsigned short)(ox[p] & 0xffff)) - 0.5f;
      const float y = ry * (float)IMG_H + bf2f((unsigned short)(ox[p] >> 16)) - 0.5f;
      const float xf = floorf(x), yf = floorf(y);
      const int ix0 = (int)xf, iy0 = (int)yf;
      const float wx1 = x - xf, wy1 = y - yf;
      const float wx0 = 1.0f - wx1, wy0 = 1.0f - wy1;

      float s = 0.0f;
#pragma unroll
      for (int cy = 0; cy < 2; ++cy) {
#pragma unroll
        for (int cx = 0; cx < 2; ++cx) {
          const int ix = ix0 + cx, iy = iy0 + cy;
          const bool valid = (ix >= 0) & (ix < IMG_W) & (iy >= 0) & (iy < IMG_H);
          const int cix = min(max(ix, 0), IMG_W - 1);
          const int ciy = min(max(iy, 0), IMG_H - 1);
          const float wgt = (cx ? wx1 : wx0) * (cy ? wy1 : wy0);
          s += valid ? bf2f(im[ciy * IMG_W + cix]) * wgt : 0.0f;
        }
      }
      acc += wgt4[p] * s;
    }
    o1s[qq][d] = acc * (1.0f / 128.0f);
  }
  __syncthreads();

  // ---- 5. out[q][n] = o1s[q]·W_o[:,n] + b_o[n] + query[q][n]
  {
    const int qq = tid >> 7;
    const int n = tid & 127;
    float acc = b_o[n] + q_lds[qq][n];
#pragma unroll 8
    for (int d = 0; d < 128; ++d)
      acc = fmaf(o1s[qq][d], W_o[(size_t)d * 128 + n], acc);
    out[(size_t)(q0 + qq) * 128 + n] = acc;
  }
}

// ---------------------------------------------------------------------------
extern "C" void kernel_launch(void* const* d_in, const int* in_sizes, int n_in,
                              void* d_out, int out_size, void* d_ws, size_t ws_size,
                              hipStream_t stream) {
  const float* query  = (const float*)d_in[0];
  const float* key    = (const float*)d_in[1];
  const float* value  = (const float*)d_in[2];
  const float* ref3d  = (const float*)d_in[3];
  // d_in[4] = spatial_shapes [[32,32]] (hardcoded)
  const float* W_off  = (const float*)d_in[5];
  const float* b_off  = (const float*)d_in[6];
  const float* W_attn = (const float*)d_in[7];
  const float* b_attn = (const float*)d_in[8];
  const float* W_v    = (const float*)d_in[9];
  const float* b_v    = (const float*)d_in[10];
  const float* W_o    = (const float*)d_in[11];
  const float* b_o    = (const float*)d_in[12];
  float* out = (float*)d_out;

  mono_kernel<<<NQ / QB, 512, 0, stream>>>(query, key, value, ref3d,
                                           W_off, b_off, W_attn, b_attn,
                                           W_v, b_v, W_o, b_o, out);
}

// Round 8
// 105.522 us; speedup vs baseline: 1.1494x; 1.1494x over previous
//
#include <hip/hip_runtime.h>
#include <hip/hip_bf16.h>

// UVCrossAttention — MI355X (gfx950), Round 11: R9 structure, 1024 threads.
//
// R10 post-mortem: direct-global MFMA operands REGRESSED (36 -> 53-57 µs)
// because VGPR collapsed to 48 -> compiler serialized the per-fragment loads
// (no MLP). Reverting to R9's staged-LDS value path (best measured) and
// attacking its latency exposure with occupancy instead:
//   * 1024 thr/block = 16 waves/CU (4/SIMD: 2 streaming + 2 MFMA), doubling
//     in-flight loads on both concurrent L2 streams.
//   * streaming half: 512 threads own 2 off-cols + 1 aw-col each.
//   * value half: 8 MFMA waves own 128 v-rows each (4 subtiles x 32 rows,
//     wave-local 8 KB LDS buffers, no barriers in the loop).
//   * bf_rne via __float2bfloat16 (compiler emits packed cvt; m240).
// One dispatch, zero workspace, 4 barriers. LDS 92 KB, 1 block/CU.
// 256 blocks x 1024 thr.

#define NQ   1024
#define NV   1024
#define ND   128
#define NP   4
#define IMG_W 32
#define IMG_H 32
#define QB   4

typedef __attribute__((ext_vector_type(8))) short bfx8;
typedef __attribute__((ext_vector_type(4))) float f32x4;

__device__ __forceinline__ unsigned short bf_rne(float f) {
  union { __hip_bfloat16 h; unsigned short u; } v;
  v.h = __float2bfloat16(f);
  return v.u;
}
__device__ __forceinline__ float bf2f(unsigned short u) {
  return __uint_as_float((unsigned)u << 16);
}
__device__ __forceinline__ bfx8 pack8(const float* p) {
  bfx8 v;
#pragma unroll
  for (int j = 0; j < 8; ++j) v[j] = (short)bf_rne(p[j]);
  return v;
}

__global__ __launch_bounds__(1024, 4) void mono_kernel(
    const float* __restrict__ query, const float* __restrict__ key,
    const float* __restrict__ value, const float* __restrict__ ref3d,
    const float* __restrict__ W_off, const float* __restrict__ b_off,
    const float* __restrict__ W_attn, const float* __restrict__ b_attn,
    const float* __restrict__ W_v, const float* __restrict__ b_v,
    const float* __restrict__ W_o, const float* __restrict__ b_o,
    float* __restrict__ out) {
  __shared__ float q_lds[QB][128];                    // 2 KB
  __shared__ float key_lds[QB][128];                  // 2 KB
  __shared__ float keyp_lds[QB][128];                 // 2 KB
  __shared__ float c_lds[QB];
  __shared__ unsigned short img_bf[QB][NV];           // 8 KB
  __shared__ unsigned short off_bf[QB][1024];         // 8 KB
  __shared__ unsigned short aw_bf[QB][512];           // 4 KB
  __shared__ float o1s[QB][128];                      // 2 KB
  __shared__ __align__(16) unsigned short sval[8 * 4096];  // 64 KB (8 x 8 KB)

  const int tid = threadIdx.x;
  const int q0 = blockIdx.x * QB;
  const int w = tid >> 6, l = tid & 63;
  const int col = l & 15, g = l >> 4;

  // ---- 1. stage q & key rows; stage W_v bf16-swizzled into sval[0..32K)
  if (tid < 128) {
    ((float4*)q_lds)[tid] = ((const float4*)(query + (size_t)q0 * 128))[tid];
  } else if (tid < 256) {
    ((float4*)key_lds)[tid - 128] =
        ((const float4*)(key + (size_t)q0 * 128))[tid - 128];
  }
#pragma unroll
  for (int it = 0; it < 2; ++it) {
    const int c = tid + it * 1024;         // 2048 chunks of 8 floats
    const int r = c >> 4, cc = c & 15;
    const bfx8 v = pack8(W_v + (size_t)r * 128 + cc * 8);
    const int byte = r * 256 + ((cc * 16) ^ ((r & 15) << 4));
    *(bfx8*)((char*)sval + byte) = v;
  }
  __syncthreads();

  // ---- 2. keyp = key @ W_v^T (waves 0..7: wave w -> embed rows w*16..+15)
  if (w < 8) {
    bfx8 afK[4];
#pragma unroll
    for (int ks = 0; ks < 4; ++ks) {
      bfx8 a;
      if (col < QB) {
        a = pack8(&key_lds[col][ks * 32 + g * 8]);
      } else {
#pragma unroll
        for (int j = 0; j < 8; ++j) a[j] = 0;
      }
      afK[ks] = a;
    }
    const int r = w * 16 + col;            // W_v row = keyp embed index
    f32x4 acc = {0.f, 0.f, 0.f, 0.f};
#pragma unroll
    for (int ks = 0; ks < 4; ++ks) {
      const int colb = (ks * 64 + g * 16) ^ (col << 4);
      const bfx8 bfr = *(const bfx8*)((const char*)sval + r * 256 + colb);
      acc = __builtin_amdgcn_mfma_f32_16x16x32_bf16(afK[ks], bfr, acc,
                                                    0, 0, 0);
    }
    if (g == 0) {
#pragma unroll
      for (int i = 0; i < QB; ++i) keyp_lds[i][r] = acc[i];
    }
  }
  if (tid < QB) {   // c[qq] = key[qq]·b_v (b_v == 0 here; kept for generality)
    float s = 0.f;
    for (int e = 0; e < 128; e += 4) {
      const float4 bv = *(const float4*)(b_v + e);
      const float4 k4 = *(const float4*)(&key_lds[tid][e]);
      s = fmaf(bv.x, k4.x,
          fmaf(bv.y, k4.y, fmaf(bv.z, k4.z, fmaf(bv.w, k4.w, s))));
    }
    c_lds[tid] = s;
  }
  __syncthreads();

  // ---- 3. SPLIT: waves 0-7 -> off/aw streaming; waves 8-15 -> img MFMA
  if (w < 8) {
    // thread t (0..511) owns off cols 2t..2t+1, aw col t
    const int t = tid;
    float2 aoff[QB];
    float aaw[QB];
#pragma unroll
    for (int qq = 0; qq < QB; ++qq) {
      aoff[qq] = make_float2(0.f, 0.f);
      aaw[qq] = 0.f;
    }
    const float* wo_p = W_off + (size_t)t * 2;
    const float* wa_p = W_attn + t;
#pragma unroll 8
    for (int e4 = 0; e4 < 32; ++e4) {
      float4 q4[QB];
#pragma unroll
      for (int qq = 0; qq < QB; ++qq)
        q4[qq] = *(const float4*)(&q_lds[qq][e4 * 4]);
#pragma unroll
      for (int j = 0; j < 4; ++j) {
        const int e = e4 * 4 + j;
        const float2 w2 = *(const float2*)(wo_p + (size_t)e * 1024);
        const float wa = wa_p[(size_t)e * 512];
#pragma unroll
        for (int qq = 0; qq < QB; ++qq) {
          const float qv = ((const float*)&q4[qq])[j];  // static (j unrolled)
          aoff[qq].x = fmaf(qv, w2.x, aoff[qq].x);
          aoff[qq].y = fmaf(qv, w2.y, aoff[qq].y);
          aaw[qq] = fmaf(qv, wa, aaw[qq]);
        }
      }
    }
    const float2 bo2 = *(const float2*)(b_off + t * 2);
    const float ba = b_attn[t];
#pragma unroll
    for (int qq = 0; qq < QB; ++qq) {
      const unsigned px = (unsigned)bf_rne(aoff[qq].x + bo2.x) |
                          ((unsigned)bf_rne(aoff[qq].y + bo2.y) << 16);
      *(unsigned*)(&off_bf[qq][t * 2]) = px;
      aw_bf[qq][t] = bf_rne(aaw[qq] + ba);
    }
  } else {
    // wave ww (0..7) owns v rows ww*128..+127: 4 subtiles of 32 rows,
    // wave-local 8 KB buffer, same-wave ds ordering, no barriers.
    const int ww = w - 8;
    unsigned short* buf = sval + ww * 4096;
    bfx8 afrag[4];
#pragma unroll
    for (int ks = 0; ks < 4; ++ks) {
      bfx8 a;
      if (col < QB) {
        a = pack8(&keyp_lds[col][ks * 32 + g * 8]);
      } else {
#pragma unroll
        for (int j = 0; j < 8; ++j) a[j] = 0;
      }
      afrag[ks] = a;
    }
    float cq[QB];
#pragma unroll
    for (int i = 0; i < QB; ++i) cq[i] = c_lds[i];

    for (int sub = 0; sub < 4; ++sub) {
      const int vbase = ww * 128 + sub * 32;
#pragma unroll
      for (int it = 0; it < 8; ++it) {
        const int c = l + it * 64;           // 512 chunks of 8 floats
        const int r = c >> 4, cc = c & 15;
        const bfx8 v = pack8(value + (size_t)(vbase + r) * 128 + cc * 8);
        const int byte = r * 256 + ((cc * 16) ^ ((r & 15) << 4));
        *(bfx8*)((char*)buf + byte) = v;
      }
#pragma unroll
      for (int cg = 0; cg < 2; ++cg) {
        const int r = cg * 16 + col;         // row within 32-row subtile
        f32x4 acc = {0.f, 0.f, 0.f, 0.f};
#pragma unroll
        for (int ks = 0; ks < 4; ++ks) {
          const int colb = (ks * 64 + g * 16) ^ (col << 4);
          const bfx8 bfr = *(const bfx8*)((const char*)buf + r * 256 + colb);
          acc = __builtin_amdgcn_mfma_f32_16x16x32_bf16(afrag[ks], bfr, acc,
                                                        0, 0, 0);
        }
        if (g == 0) {
          const int v = vbase + r;
#pragma unroll
          for (int i = 0; i < QB; ++i)
            img_bf[i][v] = bf_rne(acc[i] + cq[i]);
        }
      }
    }
  }
  __syncthreads();

  // ---- 4. sampling: threads 0..511, (qq,d) = (tid>>7, tid&127)
  if (tid < 512) {
    const int qq = tid >> 7;
    const int q = q0 + qq;
    const int d = tid & 127;
    const unsigned short* im = img_bf[qq];
    const size_t qe = (size_t)q * ND + d;

    const float rx = ref3d[qe * 2 + 0];
    const float ry = ref3d[qe * 2 + 1];

    const uint2 ua = *(const uint2*)(&aw_bf[qq][d * 4]);
    const float a0 = bf2f((unsigned short)(ua.x & 0xffff));
    const float a1 = bf2f((unsigned short)(ua.x >> 16));
    const float a2 = bf2f((unsigned short)(ua.y & 0xffff));
    const float a3 = bf2f((unsigned short)(ua.y >> 16));
    const float mx = fmaxf(fmaxf(a0, a1), fmaxf(a2, a3));
    const float e0 = __expf(a0 - mx), e1 = __expf(a1 - mx),
                e2 = __expf(a2 - mx), e3 = __expf(a3 - mx);
    const float inv = 1.0f / (e0 + e1 + e2 + e3);
    const float wgt4[4] = {e0 * inv, e1 * inv, e2 * inv, e3 * inv};

    const uint4 uo = *(const uint4*)(&off_bf[qq][d * 8]);
    const unsigned ox[4] = {uo.x, uo.y, uo.z, uo.w};

    float acc = 0.0f;
#pragma unroll
    for (int p = 0; p < NP; ++p) {
      const float x = rx * (float)IMG_W + bf2f((unsigned short)(ox[p] & 0xffff)) - 0.5f;
      const float y = ry * (float)IMG_H + bf2f((unsigned short)(ox[p] >> 16)) - 0.5f;
      const float xf = floorf(x), yf = floorf(y);
      const int ix0 = (int)xf, iy0 = (int)yf;
      const float wx1 = x - xf, wy1 = y - yf;
      const float wx0 = 1.0f - wx1, wy0 = 1.0f - wy1;

      float s = 0.0f;
#pragma unroll
      for (int cy = 0; cy < 2; ++cy) {
#pragma unroll
        for (int cx = 0; cx < 2; ++cx) {
          const int ix = ix0 + cx, iy = iy0 + cy;
          const bool valid = (ix >= 0) & (ix < IMG_W) & (iy >= 0) & (iy < IMG_H);
          const int cix = min(max(ix, 0), IMG_W - 1);
          const int ciy = min(max(iy, 0), IMG_H - 1);
          const float wgt = (cx ? wx1 : wx0) * (cy ? wy1 : wy0);
          s += valid ? bf2f(im[ciy * IMG_W + cix]) * wgt : 0.0f;
        }
      }
      acc += wgt4[p] * s;
    }
    o1s[qq][d] = acc * (1.0f / 128.0f);
  }
  __syncthreads();

  // ---- 5. out[q][n] = o1s[q]·W_o[:,n] + b_o[n] + query[q][n]  (tid<512)
  if (tid < 512) {
    const int qq = tid >> 7;
    const int n = tid & 127;
    float acc = b_o[n] + q_lds[qq][n];
#pragma unroll 8
    for (int d = 0; d < 128; ++d)
      acc = fmaf(o1s[qq][d], W_o[(size_t)d * 128 + n], acc);
    out[(size_t)(q0 + qq) * 128 + n] = acc;
  }
}

// ---------------------------------------------------------------------------
extern "C" void kernel_launch(void* const* d_in, const int* in_sizes, int n_in,
                              void* d_out, int out_size, void* d_ws, size_t ws_size,
                              hipStream_t stream) {
  const float* query  = (const float*)d_in[0];
  const float* key    = (const float*)d_in[1];
  const float* value  = (const float*)d_in[2];
  const float* ref3d  = (const float*)d_in[3];
  // d_in[4] = spatial_shapes [[32,32]] (hardcoded)
  const float* W_off  = (const float*)d_in[5];
  const float* b_off  = (const float*)d_in[6];
  const float* W_attn = (const float*)d_in[7];
  const float* b_attn = (const float*)d_in[8];
  const float* W_v    = (const float*)d_in[9];
  const float* b_v    = (const float*)d_in[10];
  const float* W_o    = (const float*)d_in[11];
  const float* b_o    = (const float*)d_in[12];
  float* out = (float*)d_out;

  mono_kernel<<<NQ / QB, 1024, 0, stream>>>(query, key, value, ref3d,
                                            W_off, b_off, W_attn, b_attn,
                                            W_v, b_v, W_o, b_o, out);
}